// Round 1
// baseline (268.347 us; speedup 1.0000x reference)
//
#include <hip/hip_runtime.h>

#define BLK  256   // threads per block = query points per block
#define TILE 1024  // reference points staged in LDS per pass

__global__ __launch_bounds__(BLK) void chamfer_kernel(
    const float* __restrict__ preds,
    const float* __restrict__ gts,
    float* __restrict__ out,
    int N)
{
    const int b   = blockIdx.y;
    const int dir = blockIdx.z;
    // dir 0: queries = gts (loss_2), refs = preds
    // dir 1: queries = preds (loss_1), refs = gts
    const float* q = ((dir == 0) ? gts   : preds) + (size_t)b * N * 3;
    const float* r = ((dir == 0) ? preds : gts)   + (size_t)b * N * 3;

    __shared__ float px[TILE];
    __shared__ float py[TILE];
    __shared__ float pz[TILE];
    __shared__ float wsum[BLK / 64];

    const int tid = threadIdx.x;
    const int qi  = blockIdx.x * BLK + tid;

    const float qx = q[qi * 3 + 0];
    const float qy = q[qi * 3 + 1];
    const float qz = q[qi * 3 + 2];

    float b0 = 3.4e38f, b1 = 3.4e38f, b2 = 3.4e38f, b3 = 3.4e38f;

    for (int t0 = 0; t0 < N; t0 += TILE) {
        __syncthreads();
        // cooperative AoS -> SoA staging: 3*TILE floats, coalesced global reads
        #pragma unroll
        for (int idx = tid; idx < 3 * TILE; idx += BLK) {
            float v = r[t0 * 3 + idx];
            int k = idx / 3;
            int c = idx - k * 3;
            if (c == 0)      px[k] = v;
            else if (c == 1) py[k] = v;
            else             pz[k] = v;
        }
        __syncthreads();

        #pragma unroll 2
        for (int k = 0; k < TILE; k += 4) {
            float4 X = *(const float4*)&px[k];
            float4 Y = *(const float4*)&py[k];
            float4 Z = *(const float4*)&pz[k];

            float dx, dy, dz, d;
            dx = qx - X.x; dy = qy - Y.x; dz = qz - Z.x;
            d  = dx * dx + dy * dy + dz * dz;
            b0 = fminf(b0, d);
            dx = qx - X.y; dy = qy - Y.y; dz = qz - Z.y;
            d  = dx * dx + dy * dy + dz * dz;
            b1 = fminf(b1, d);
            dx = qx - X.z; dy = qy - Y.z; dz = qz - Z.z;
            d  = dx * dx + dy * dy + dz * dz;
            b2 = fminf(b2, d);
            dx = qx - X.w; dy = qy - Y.w; dz = qz - Z.w;
            d  = dx * dx + dy * dy + dz * dz;
            b3 = fminf(b3, d);
        }
    }

    float best = fminf(fminf(b0, b1), fminf(b2, b3));

    // wave64 shuffle reduce (sum of per-query mins)
    float s = best;
    #pragma unroll
    for (int off = 32; off > 0; off >>= 1)
        s += __shfl_down(s, off, 64);

    if ((tid & 63) == 0) wsum[tid >> 6] = s;
    __syncthreads();
    if (tid == 0) {
        float tot = 0.0f;
        #pragma unroll
        for (int w = 0; w < BLK / 64; ++w) tot += wsum[w];
        atomicAdd(out, tot);
    }
}

extern "C" void kernel_launch(void* const* d_in, const int* in_sizes, int n_in,
                              void* d_out, int out_size, void* d_ws, size_t ws_size,
                              hipStream_t stream) {
    const float* preds = (const float*)d_in[0];
    const float* gts   = (const float*)d_in[1];
    float* out = (float*)d_out;

    const int B = 8;
    const int N = 8192;

    hipMemsetAsync(out, 0, sizeof(float), stream);

    dim3 grid(N / BLK, B, 2);
    dim3 block(BLK);
    chamfer_kernel<<<grid, block, 0, stream>>>(preds, gts, out, N);
}